// Round 1
// baseline (9178.571 us; speedup 1.0000x reference)
//
#include <hip/hip_runtime.h>
#include <hip/hip_bf16.h>

// Problem constants (fixed by the reference).
#define TT 20
#define NN 50000
#define EE 800000
#define IND 16
#define HH 128
#define NPF 7

// ---------------------------------------------------------------------------
// Edge-dtype detection: if edge_index is int64, every odd int32 word (high
// half, values < 2^31) is zero. Genuine int32 edges are random in [0,50000):
// 1024 consecutive zeros is impossible. flag=1 -> int64, flag=0 -> int32.
__global__ void detect_kernel(const int* ei, int* flag, int E) {
    __shared__ int nz;
    if (threadIdx.x == 0) nz = 0;
    __syncthreads();
    for (int i = threadIdx.x; i < 1024 && i < E; i += blockDim.x)
        if (ei[2 * i + 1] != 0) atomicOr(&nz, 1);
    __syncthreads();
    if (threadIdx.x == 0) *flag = (nz == 0) ? 1 : 0;
}

__device__ __forceinline__ int edge_src(const int* ei, int e, int E, int f) {
    return f ? ei[2 * e] : ei[e];
}
__device__ __forceinline__ int edge_dst(const int* ei, int e, int E, int f) {
    return f ? ei[2 * (E + e)] : ei[E + e];
}

__global__ void count_deg_kernel(const int* ei, const int* flag, int* deg, int E) {
    int e = blockIdx.x * blockDim.x + threadIdx.x;
    if (e >= E) return;
    int f = *flag;
    atomicAdd(&deg[edge_dst(ei, e, E, f)], 1);
}

// Single-block exclusive scan of deg -> offsets (+cursor copy, +deg_inv).
__global__ void scan_kernel(const int* deg, int* offs, int* cursor, float* dinv,
                            int N, int E) {
    __shared__ int part[1024];
    const int tid = threadIdx.x;
    const int CH = (N + 1023) / 1024;
    int s0 = tid * CH;
    int s1 = s0 + CH; if (s1 > N) s1 = N;
    int sum = 0;
    for (int n = s0; n < s1; ++n) sum += deg[n];
    part[tid] = sum;
    __syncthreads();
    for (int off = 1; off < 1024; off <<= 1) {
        int v = (tid >= off) ? part[tid - off] : 0;
        __syncthreads();
        part[tid] += v;
        __syncthreads();
    }
    int run = (tid == 0) ? 0 : part[tid - 1];
    for (int n = s0; n < s1; ++n) {
        offs[n] = run;
        cursor[n] = run;
        int d = deg[n];
        dinv[n] = 1.0f / (float)(d > 1 ? d : 1);
        run += d;
    }
    if (tid == 0) offs[N] = E;
}

__global__ void fill_csr_kernel(const int* ei, const int* flag, int* cursor,
                                int* csr, int E) {
    int e = blockIdx.x * blockDim.x + threadIdx.x;
    if (e >= E) return;
    int f = *flag;
    int s = edge_src(ei, e, E, f);
    int d = edge_dst(ei, e, E, f);
    int p = atomicAdd(&cursor[d], 1);
    csr[p] = s;
}

// GRU weights are [3H,H] used as x @ W^T: pre-transpose to [H][3H].
__global__ void gru_transpose_kernel(const float* wih, const float* whh,
                                     float* wihT, float* whhT) {
    int id = blockIdx.x * blockDim.x + threadIdx.x;
    if (id >= 3 * HH * HH) return;
    int j = id / HH, k = id % HH;
    wihT[k * (3 * HH) + j] = wih[id];
    whhT[k * (3 * HH) + j] = whh[id];
}

// ---------------------------------------------------------------------------
// SAGE layer 1 aggregation: one thread per (node, in-feature).
__global__ void sage1_agg_kernel(const float* xt, const int* offs, const int* csr,
                                 const float* dinv, float* agg1) {
    int id = blockIdx.x * blockDim.x + threadIdx.x;
    if (id >= NN * IND) return;
    int n = id >> 4, c = id & 15;
    int e0 = offs[n], e1 = offs[n + 1];
    float s = 0.f;
    for (int e = e0; e < e1; ++e) s += xt[csr[e] * IND + c];
    agg1[id] = s * dinv[n];
}

// h1 = relu(agg1 @ wl + bl + x @ wr) ; 8 nodes/block, 128 threads (1/out col).
__global__ __launch_bounds__(128) void sage1_gemm_kernel(
    const float* agg1, const float* xt, const float* wl, const float* bl,
    const float* wr, float* h1) {
    const int col = threadIdx.x;
    const int m0 = blockIdx.x * 8;
    __shared__ float sA[8][IND], sX[8][IND];
    {
        int r = col >> 4, c = col & 15;
        sA[r][c] = agg1[(m0 + r) * IND + c];
        sX[r][c] = xt[(m0 + r) * IND + c];
    }
    __syncthreads();
    float acc[8];
    float b = bl[col];
#pragma unroll
    for (int m = 0; m < 8; ++m) acc[m] = b;
#pragma unroll
    for (int k = 0; k < IND; ++k) {
        float wlv = wl[k * HH + col];
        float wrv = wr[k * HH + col];
#pragma unroll
        for (int m = 0; m < 8; ++m) acc[m] += sA[m][k] * wlv + sX[m][k] * wrv;
    }
#pragma unroll
    for (int m = 0; m < 8; ++m) h1[(m0 + m) * HH + col] = fmaxf(acc[m], 0.f);
}

// SAGE layer 2 aggregation: one block per node, one thread per feature.
__global__ __launch_bounds__(128) void sage2_agg_kernel(
    const float* h1, const int* offs, const int* csr, const float* dinv,
    float* agg2) {
    int n = blockIdx.x, col = threadIdx.x;
    int e0 = offs[n], e1 = offs[n + 1];
    float s = 0.f;
    for (int e = e0; e < e1; ++e) s += h1[csr[e] * HH + col];
    agg2[n * HH + col] = s * dinv[n];
}

// enc = LN(relu(agg2 @ wl + bl + h1 @ wr)) ; in-place over agg2 is safe
// (each block reads its own rows into LDS before writing them).
__global__ __launch_bounds__(128) void sage2_gemm_ln_kernel(
    const float* agg2, const float* h1, const float* wl, const float* bl,
    const float* wr, const float* lng, const float* lnb, float* enc) {
    const int col = threadIdx.x;
    const int m0 = blockIdx.x * 8;
    __shared__ float sA[8][HH], sH[8][HH];
    __shared__ float sMu[8], sRstd[8];
#pragma unroll
    for (int m = 0; m < 8; ++m) {
        sA[m][col] = agg2[(m0 + m) * HH + col];
        sH[m][col] = h1[(m0 + m) * HH + col];
    }
    __syncthreads();
    float acc[8];
    float b = bl[col];
#pragma unroll
    for (int m = 0; m < 8; ++m) acc[m] = b;
    for (int k = 0; k < HH; ++k) {
        float wlv = wl[k * HH + col];
        float wrv = wr[k * HH + col];
#pragma unroll
        for (int m = 0; m < 8; ++m) acc[m] += sA[m][k] * wlv + sH[m][k] * wrv;
    }
    __syncthreads();
#pragma unroll
    for (int m = 0; m < 8; ++m) sA[m][col] = fmaxf(acc[m], 0.f);
    __syncthreads();
    // 16 threads per node: mean / var reduction.
    int g = col >> 4, l = col & 15;
    float s = 0.f, q = 0.f;
#pragma unroll
    for (int i = 0; i < 8; ++i) {
        float v = sA[g][l + 16 * i];
        s += v; q += v * v;
    }
#pragma unroll
    for (int off = 8; off >= 1; off >>= 1) {
        s += __shfl_xor(s, off, 16);
        q += __shfl_xor(q, off, 16);
    }
    if (l == 0) {
        float mu = s * (1.f / 128.f);
        float var = q * (1.f / 128.f) - mu * mu;
        sMu[g] = mu;
        sRstd[g] = rsqrtf(var + 1e-5f);
    }
    __syncthreads();
    float gg = lng[col], bb = lnb[col];
#pragma unroll
    for (int m = 0; m < 8; ++m)
        enc[(m0 + m) * HH + col] = (sA[m][col] - sMu[m]) * sRstd[m] * gg + bb;
}

// GRU step: h updated in place (rows staged to LDS first).
__global__ __launch_bounds__(128) void gru_kernel(
    const float* enc, float* h, const float* wihT, const float* whhT,
    const float* bih, const float* bhh) {
    const int col = threadIdx.x;
    const int m0 = blockIdx.x * 8;
    __shared__ float sE[8][HH], sH[8][HH];
#pragma unroll
    for (int m = 0; m < 8; ++m) {
        sE[m][col] = enc[(m0 + m) * HH + col];
        sH[m][col] = h[(m0 + m) * HH + col];
    }
    __syncthreads();
    float air[8], aiz[8], ain[8], ahr[8], ahz[8], ahn[8];
    float bir = bih[col], biz = bih[HH + col], bin = bih[2 * HH + col];
    float bhr = bhh[col], bhz = bhh[HH + col], bhn = bhh[2 * HH + col];
#pragma unroll
    for (int m = 0; m < 8; ++m) {
        air[m] = bir; aiz[m] = biz; ain[m] = bin;
        ahr[m] = bhr; ahz[m] = bhz; ahn[m] = bhn;
    }
    for (int k = 0; k < HH; ++k) {
        const float* wi = wihT + k * (3 * HH);
        const float* wh = whhT + k * (3 * HH);
        float wir = wi[col], wiz = wi[HH + col], win = wi[2 * HH + col];
        float whr = wh[col], whz = wh[HH + col], whn = wh[2 * HH + col];
#pragma unroll
        for (int m = 0; m < 8; ++m) {
            float e = sE[m][k], hv = sH[m][k];
            air[m] += e * wir; aiz[m] += e * wiz; ain[m] += e * win;
            ahr[m] += hv * whr; ahz[m] += hv * whz; ahn[m] += hv * whn;
        }
    }
#pragma unroll
    for (int m = 0; m < 8; ++m) {
        float r = 1.f / (1.f + expf(-(air[m] + ahr[m])));
        float z = 1.f / (1.f + expf(-(aiz[m] + ahz[m])));
        float nn = tanhf(ain[m] + r * ahn[m]);
        h[(m0 + m) * HH + col] = (1.f - z) * nn + z * sH[m][col];
    }
}

// Both decoders fused: th = relu(h@tw1+tb1)@tw2+tb2 ; ph likewise (7 outs).
__global__ __launch_bounds__(128) void dec_kernel(
    const float* h, const float* tw1, const float* tb1, const float* tw2,
    const float* tb2, const float* pw1, const float* pb1, const float* pw2,
    const float* pb2, float* out_th, float* out_ph) {
    const int col = threadIdx.x;
    const int m0 = blockIdx.x * 8;
    __shared__ float sHh[8][HH];
    __shared__ float sTH[8][HH];
    __shared__ float sPH[8][HH];
#pragma unroll
    for (int m = 0; m < 8; ++m) sHh[m][col] = h[(m0 + m) * HH + col];
    __syncthreads();
    float at[8], ap[8];
    float bt = tb1[col], bp = pb1[col];
#pragma unroll
    for (int m = 0; m < 8; ++m) { at[m] = bt; ap[m] = bp; }
    for (int k = 0; k < HH; ++k) {
        float w1 = tw1[k * HH + col];
        float w2 = pw1[k * HH + col];
#pragma unroll
        for (int m = 0; m < 8; ++m) {
            float hv = sHh[m][k];
            at[m] += hv * w1;
            ap[m] += hv * w2;
        }
    }
    float tw2v = tw2[col];
    __syncthreads();
#pragma unroll
    for (int m = 0; m < 8; ++m) {
        sTH[m][col] = fmaxf(at[m], 0.f) * tw2v;
        sPH[m][col] = fmaxf(ap[m], 0.f);
    }
    __syncthreads();
    // thickness: 16 threads per node reduce 128 products
    int g = col >> 4, l = col & 15;
    float s = 0.f;
#pragma unroll
    for (int i = 0; i < 8; ++i) s += sTH[g][l + 16 * i];
#pragma unroll
    for (int off = 8; off >= 1; off >>= 1) s += __shfl_xor(s, off, 16);
    if (l == 0) out_th[m0 + g] = s + tb2[0];
    // physical features: 56 threads, one per (node, feature)
    if (col < 56) {
        int m = col / 7, f = col % 7;
        float acc = pb2[f];
        for (int c = 0; c < HH; ++c) acc += sPH[m][c] * pw2[c * NPF + f];
        out_ph[(m0 + m) * NPF + f] = acc;
    }
}

// ---------------------------------------------------------------------------
extern "C" void kernel_launch(void* const* d_in, const int* in_sizes, int n_in,
                              void* d_out, int out_size, void* d_ws, size_t ws_size,
                              hipStream_t stream) {
    const float* x      = (const float*)d_in[0];
    const int*   ei     = (const int*)d_in[1];
    const float* s1wl   = (const float*)d_in[2];
    const float* s1bl   = (const float*)d_in[3];
    const float* s1wr   = (const float*)d_in[4];
    const float* s2wl   = (const float*)d_in[5];
    const float* s2bl   = (const float*)d_in[6];
    const float* s2wr   = (const float*)d_in[7];
    const float* lng    = (const float*)d_in[8];
    const float* lnb    = (const float*)d_in[9];
    const float* g_wih  = (const float*)d_in[10];
    const float* g_whh  = (const float*)d_in[11];
    const float* g_bih  = (const float*)d_in[12];
    const float* g_bhh  = (const float*)d_in[13];
    const float* tw1    = (const float*)d_in[14];
    const float* tb1    = (const float*)d_in[15];
    const float* tw2    = (const float*)d_in[16];
    const float* tb2    = (const float*)d_in[17];
    const float* pw1    = (const float*)d_in[18];
    const float* pb1    = (const float*)d_in[19];
    const float* pw2    = (const float*)d_in[20];
    const float* pb2    = (const float*)d_in[21];

    char* ws = (char*)d_ws;
    size_t o = 0;
    auto alloc = [&](size_t bytes) {
        size_t r = o;
        o += (bytes + 255) & ~(size_t)255;
        return r;
    };
    int*   flag   = (int*)(ws + alloc(4));
    int*   deg    = (int*)(ws + alloc((size_t)NN * 4));
    int*   offs   = (int*)(ws + alloc((size_t)(NN + 1) * 4));
    int*   cursor = (int*)(ws + alloc((size_t)NN * 4));
    int*   csr    = (int*)(ws + alloc((size_t)EE * 4));
    float* dinv   = (float*)(ws + alloc((size_t)NN * 4));
    float* wihT   = (float*)(ws + alloc((size_t)3 * HH * HH * 4));
    float* whhT   = (float*)(ws + alloc((size_t)3 * HH * HH * 4));
    float* agg1   = (float*)(ws + alloc((size_t)NN * IND * 4));
    float* h1     = (float*)(ws + alloc((size_t)NN * HH * 4));
    float* buf2   = (float*)(ws + alloc((size_t)NN * HH * 4));   // agg2 / enc
    float* hbuf   = (float*)(ws + alloc((size_t)NN * HH * 4));   // GRU state

    // Graph prep (identical work every call -> graph-capture safe).
    detect_kernel<<<1, 256, 0, stream>>>(ei, flag, EE);
    hipMemsetAsync(deg, 0, (size_t)NN * 4, stream);
    count_deg_kernel<<<(EE + 255) / 256, 256, 0, stream>>>(ei, flag, deg, EE);
    scan_kernel<<<1, 1024, 0, stream>>>(deg, offs, cursor, dinv, NN, EE);
    fill_csr_kernel<<<(EE + 255) / 256, 256, 0, stream>>>(ei, flag, cursor, csr, EE);
    gru_transpose_kernel<<<(3 * HH * HH + 255) / 256, 256, 0, stream>>>(
        g_wih, g_whh, wihT, whhT);
    hipMemsetAsync(hbuf, 0, (size_t)NN * HH * 4, stream);

    float* out = (float*)d_out;
    for (int t = 0; t < TT; ++t) {
        const float* xt = x + (size_t)t * NN * IND;
        sage1_agg_kernel<<<(NN * IND + 255) / 256, 256, 0, stream>>>(
            xt, offs, csr, dinv, agg1);
        sage1_gemm_kernel<<<NN / 8, 128, 0, stream>>>(agg1, xt, s1wl, s1bl, s1wr, h1);
        sage2_agg_kernel<<<NN, 128, 0, stream>>>(h1, offs, csr, dinv, buf2);
        sage2_gemm_ln_kernel<<<NN / 8, 128, 0, stream>>>(
            buf2, h1, s2wl, s2bl, s2wr, lng, lnb, buf2);
        gru_kernel<<<NN / 8, 128, 0, stream>>>(buf2, hbuf, wihT, whhT, g_bih, g_bhh);
        dec_kernel<<<NN / 8, 128, 0, stream>>>(
            hbuf, tw1, tb1, tw2, tb2, pw1, pb1, pw2, pb2,
            out + (size_t)t * NN, out + (size_t)TT * NN + (size_t)t * NN * NPF);
    }
}

// Round 2
// 3900.767 us; speedup vs baseline: 2.3530x; 2.3530x over previous
//
#include <hip/hip_runtime.h>
#include <hip/hip_bf16.h>

#define TT 20
#define NN 50000
#define EE 800000
#define IND 16
#define HH 128
#define NPF 7

typedef __attribute__((ext_vector_type(8))) short bf16x8;
typedef __attribute__((ext_vector_type(4))) float f32x4;
#define MFMA(a, b, c) __builtin_amdgcn_mfma_f32_16x16x32_bf16(a, b, c, 0, 0, 0)

__device__ __forceinline__ unsigned short f2bf(float f) {
    union { float f; unsigned u; } v; v.f = f;
    unsigned r = v.u + 0x7fffu + ((v.u >> 16) & 1u);
    return (unsigned short)(r >> 16);
}
__device__ __forceinline__ float bf2f(unsigned short u) {
    union { unsigned u; float f; } v; v.u = ((unsigned)u) << 16;
    return v.f;
}

// ---------------------------------------------------------------------------
// Edge-dtype detection (int64 vs int32), CSR build — unchanged from round 1.
__global__ void detect_kernel(const int* ei, int* flag, int E) {
    __shared__ int nz;
    if (threadIdx.x == 0) nz = 0;
    __syncthreads();
    for (int i = threadIdx.x; i < 1024 && i < E; i += blockDim.x)
        if (ei[2 * i + 1] != 0) atomicOr(&nz, 1);
    __syncthreads();
    if (threadIdx.x == 0) *flag = (nz == 0) ? 1 : 0;
}
__device__ __forceinline__ int edge_src(const int* ei, int e, int E, int f) {
    return f ? ei[2 * e] : ei[e];
}
__device__ __forceinline__ int edge_dst(const int* ei, int e, int E, int f) {
    return f ? ei[2 * (E + e)] : ei[E + e];
}
__global__ void count_deg_kernel(const int* ei, const int* flag, int* deg, int E) {
    int e = blockIdx.x * blockDim.x + threadIdx.x;
    if (e >= E) return;
    int f = *flag;
    atomicAdd(&deg[edge_dst(ei, e, E, f)], 1);
}
__global__ void scan_kernel(const int* deg, int* offs, int* cursor, float* dinv,
                            int N, int E) {
    __shared__ int part[1024];
    const int tid = threadIdx.x;
    const int CH = (N + 1023) / 1024;
    int s0 = tid * CH;
    int s1 = s0 + CH; if (s1 > N) s1 = N;
    int sum = 0;
    for (int n = s0; n < s1; ++n) sum += deg[n];
    part[tid] = sum;
    __syncthreads();
    for (int off = 1; off < 1024; off <<= 1) {
        int v = (tid >= off) ? part[tid - off] : 0;
        __syncthreads();
        part[tid] += v;
        __syncthreads();
    }
    int run = (tid == 0) ? 0 : part[tid - 1];
    for (int n = s0; n < s1; ++n) {
        offs[n] = run;
        cursor[n] = run;
        int d = deg[n];
        dinv[n] = 1.0f / (float)(d > 1 ? d : 1);
        run += d;
    }
    if (tid == 0) offs[N] = E;
}
__global__ void fill_csr_kernel(const int* ei, const int* flag, int* cursor,
                                int* csr, int E) {
    int e = blockIdx.x * blockDim.x + threadIdx.x;
    if (e >= E) return;
    int f = *flag;
    int s = edge_src(ei, e, E, f);
    int d = edge_dst(ei, e, E, f);
    int p = atomicAdd(&cursor[d], 1);
    csr[p] = s;
}

// ---------------------------------------------------------------------------
// Pack a K=128 weight matrix into MFMA B-fragment order:
// frag[tile][kk][lane][i] = B[kk*32+(lane>>4)*8+i][tile*16+(lane&15)]
// mode 0: B[k][n] = src[k*(tiles*16)+n]   (row-major [K][Ncols])
// mode 1: B[k][n] = src[n*128+k]          (torch [Ncols][K], used transposed)
__global__ void pack_kernel(const float* src, unsigned short* dst, int tiles,
                            int mode) {
    int id = blockIdx.x * blockDim.x + threadIdx.x;
    if (id >= tiles * 4 * 64) return;
    int lane = id & 63, kk = (id >> 6) & 3, tile = id >> 8;
    int n = tile * 16 + (lane & 15);
    int kbase = kk * 32 + (lane >> 4) * 8;
    unsigned short out[8];
#pragma unroll
    for (int i = 0; i < 8; ++i) {
        int k = kbase + i;
        float v = mode ? src[n * HH + k] : src[k * (tiles * 16) + n];
        out[i] = f2bf(v);
    }
    *(uint4*)(dst + (size_t)id * 8) = *(uint4*)out;
}

// ---------------------------------------------------------------------------
// SAGE-1 aggregation: 4 threads/node, float4 rows.
__global__ void sage1_agg_kernel(const float* xt, const int* offs, const int* csr,
                                 const float* dinv, float* agg1) {
    int id = blockIdx.x * blockDim.x + threadIdx.x;
    if (id >= NN * 4) return;
    int n = id >> 2, c4 = (id & 3) * 4;
    int e0 = offs[n], e1 = offs[n + 1];
    float4 s = make_float4(0.f, 0.f, 0.f, 0.f);
    for (int e = e0; e < e1; ++e) {
        float4 v = *(const float4*)(xt + (size_t)csr[e] * IND + c4);
        s.x += v.x; s.y += v.y; s.z += v.z; s.w += v.w;
    }
    float di = dinv[n];
    s.x *= di; s.y *= di; s.z *= di; s.w *= di;
    *(float4*)(agg1 + (size_t)n * IND + c4) = s;
}

// h1 = relu(agg1 @ wl + bl + x @ wr), K=16 fp32, output bf16.
__global__ __launch_bounds__(128) void sage1_gemm_kernel(
    const float* agg1, const float* xt, const float* wl, const float* bl,
    const float* wr, unsigned short* h1) {
    const int col = threadIdx.x;
    const int m0 = blockIdx.x * 8;
    __shared__ float sA[8][IND], sX[8][IND];
    {
        int r = col >> 4, c = col & 15;
        sA[r][c] = agg1[(size_t)(m0 + r) * IND + c];
        sX[r][c] = xt[(size_t)(m0 + r) * IND + c];
    }
    __syncthreads();
    float acc[8];
    float b = bl[col];
#pragma unroll
    for (int m = 0; m < 8; ++m) acc[m] = b;
#pragma unroll
    for (int k = 0; k < IND; ++k) {
        float wlv = wl[k * HH + col];
        float wrv = wr[k * HH + col];
#pragma unroll
        for (int m = 0; m < 8; ++m) acc[m] += sA[m][k] * wlv + sX[m][k] * wrv;
    }
#pragma unroll
    for (int m = 0; m < 8; ++m)
        h1[(size_t)(m0 + m) * HH + col] = f2bf(fmaxf(acc[m], 0.f));
}

// SAGE-2 aggregation over bf16 h1: 2 nodes/block (1 wave each), bf16x2/lane.
__global__ __launch_bounds__(128) void sage2_agg_kernel(
    const unsigned short* h1, const int* offs, const int* csr, const float* dinv,
    unsigned short* agg2) {
    int w = threadIdx.x >> 6, lane = threadIdx.x & 63;
    int n = blockIdx.x * 2 + w;
    int e0 = offs[n], e1 = offs[n + 1];
    float s0 = 0.f, s1 = 0.f;
    for (int e = e0; e < e1; ++e) {
        unsigned v = *(const unsigned*)(h1 + (size_t)csr[e] * HH + lane * 2);
        s0 += bf2f((unsigned short)(v & 0xffff));
        s1 += bf2f((unsigned short)(v >> 16));
    }
    float di = dinv[n];
    unsigned o = (unsigned)f2bf(s0 * di) | ((unsigned)f2bf(s1 * di) << 16);
    *(unsigned*)(agg2 + (size_t)n * HH + lane * 2) = o;
}

// ---------------------------------------------------------------------------
// Fused: sage2-GEMM + LN + GRU + both decoders. 1 wave, 16 nodes per block.
// MFMA 16x16x32 bf16. A-frags from XOR-swizzled LDS; B-frags pre-packed global.
__global__ __launch_bounds__(64) void fused_kernel(
    const unsigned short* __restrict__ agg2, const unsigned short* __restrict__ h1,
    const unsigned short* __restrict__ pS2L, const unsigned short* __restrict__ pS2R,
    const float* __restrict__ s2bl, const float* __restrict__ lng,
    const float* __restrict__ lnb,
    const unsigned short* __restrict__ pGI, const unsigned short* __restrict__ pGH,
    const float* __restrict__ bih, const float* __restrict__ bhh,
    float* __restrict__ h,
    const unsigned short* __restrict__ pT1, const unsigned short* __restrict__ pP1,
    const float* __restrict__ tb1, const float* __restrict__ tw2,
    const float* __restrict__ tb2, const float* __restrict__ pb1,
    const float* __restrict__ pw2, const float* __restrict__ pb2,
    float* __restrict__ out_th, float* __restrict__ out_ph) {
    const int lane = threadIdx.x;
    const int r0 = blockIdx.x * 16;
    __shared__ unsigned short bufA[16 * 128];  // agg2 -> enc
    __shared__ unsigned short bufB[16 * 128];  // h1   -> h_new
    __shared__ unsigned short bufH[16 * 128];  // h_old bf16

    // ---- stage (16 rows x 128) x3, XOR-swizzled 16B chunks
#pragma unroll
    for (int j = 0; j < 4; ++j) {
        int off = (lane + 64 * j) * 16;  // byte offset in 4KB tile
        int row = off >> 8;
        int swz = off ^ ((row & 7) << 4);
        *(uint4*)((char*)bufA + swz) =
            *(const uint4*)((const char*)(agg2 + (size_t)r0 * HH) + off);
        *(uint4*)((char*)bufB + swz) =
            *(const uint4*)((const char*)(h1 + (size_t)r0 * HH) + off);
        const float* hs = h + (size_t)r0 * HH + (size_t)(off / 2);
        unsigned short tmp[8];
#pragma unroll
        for (int i = 0; i < 8; ++i) tmp[i] = f2bf(hs[i]);
        *(uint4*)((char*)bufH + swz) = *(uint4*)tmp;
    }
    __syncthreads();

    // A-frag read: row = lane&15, k-chunk = (lane>>4)*8 within 32-wide k-step
#define LDA(buf, kk)                                                          \
    (*(const bf16x8*)((const char*)(buf) +                                    \
        (((lane & 15) * 256 + (kk) * 64 + (lane >> 4) * 16) ^                 \
         (((lane & 15) & 7) << 4))))

    // ---- phase 1: enc = LN(relu(agg2@wl + bl + h1@wr))
    bf16x8 ae[4], ah[4];
#pragma unroll
    for (int kk = 0; kk < 4; ++kk) { ae[kk] = LDA(bufA, kk); ah[kk] = LDA(bufB, kk); }
    float vE[8][4];
    float sS[4] = {0, 0, 0, 0}, sQ[4] = {0, 0, 0, 0};
#pragma unroll
    for (int c = 0; c < 8; ++c) {
        f32x4 al = {0, 0, 0, 0}, ar = {0, 0, 0, 0};
#pragma unroll
        for (int kk = 0; kk < 4; ++kk) {
            bf16x8 bl = *(const bf16x8*)(pS2L + ((size_t)(c * 4 + kk) * 64 + lane) * 8);
            bf16x8 br = *(const bf16x8*)(pS2R + ((size_t)(c * 4 + kk) * 64 + lane) * 8);
            al = MFMA(ae[kk], bl, al);
            ar = MFMA(ah[kk], br, ar);
        }
        int col = c * 16 + (lane & 15);
        float bb = s2bl[col];
#pragma unroll
        for (int j = 0; j < 4; ++j) {
            float v = fmaxf(al[j] + ar[j] + bb, 0.f);
            vE[c][j] = v; sS[j] += v; sQ[j] += v * v;
        }
    }
#pragma unroll
    for (int o = 1; o <= 8; o <<= 1) {
#pragma unroll
        for (int j = 0; j < 4; ++j) {
            sS[j] += __shfl_xor(sS[j], o);
            sQ[j] += __shfl_xor(sQ[j], o);
        }
    }
    __syncthreads();  // ae/ah live in regs; bufA may be overwritten
#pragma unroll
    for (int c = 0; c < 8; ++c) {
        int col = c * 16 + (lane & 15);
        float g = lng[col], b = lnb[col];
#pragma unroll
        for (int j = 0; j < 4; ++j) {
            float mu = sS[j] * (1.f / 128.f);
            float var = sQ[j] * (1.f / 128.f) - mu * mu;
            float ve = (vE[c][j] - mu) * rsqrtf(var + 1e-5f) * g + b;
            int row = (lane >> 4) * 4 + j;
            int off = ((row * 128 + col) * 2) ^ ((row & 7) << 4);
            *(unsigned short*)((char*)bufA + off) = f2bf(ve);
        }
    }
    __syncthreads();

    // ---- phase 2: GRU (gi = enc@Wih^T, gh = h@Whh^T; gates fp32)
    bf16x8 xe[4], xh[4];
#pragma unroll
    for (int kk = 0; kk < 4; ++kk) { xe[kk] = LDA(bufA, kk); xh[kk] = LDA(bufH, kk); }
    float hv_[8][4];
#pragma unroll
    for (int c = 0; c < 8; ++c) {
        f32x4 air = {0,0,0,0}, aiz = {0,0,0,0}, ain = {0,0,0,0};
        f32x4 ahr = {0,0,0,0}, ahz = {0,0,0,0}, ahn = {0,0,0,0};
#pragma unroll
        for (int kk = 0; kk < 4; ++kk) {
            bf16x8 bir = *(const bf16x8*)(pGI + ((size_t)((c     ) * 4 + kk) * 64 + lane) * 8);
            bf16x8 biz = *(const bf16x8*)(pGI + ((size_t)((c +  8) * 4 + kk) * 64 + lane) * 8);
            bf16x8 bin = *(const bf16x8*)(pGI + ((size_t)((c + 16) * 4 + kk) * 64 + lane) * 8);
            bf16x8 bhr = *(const bf16x8*)(pGH + ((size_t)((c     ) * 4 + kk) * 64 + lane) * 8);
            bf16x8 bhz = *(const bf16x8*)(pGH + ((size_t)((c +  8) * 4 + kk) * 64 + lane) * 8);
            bf16x8 bhn = *(const bf16x8*)(pGH + ((size_t)((c + 16) * 4 + kk) * 64 + lane) * 8);
            air = MFMA(xe[kk], bir, air); aiz = MFMA(xe[kk], biz, aiz);
            ain = MFMA(xe[kk], bin, ain);
            ahr = MFMA(xh[kk], bhr, ahr); ahz = MFMA(xh[kk], bhz, ahz);
            ahn = MFMA(xh[kk], bhn, ahn);
        }
        int col = c * 16 + (lane & 15);
        float bir_ = bih[col], biz_ = bih[HH + col], bin_ = bih[2 * HH + col];
        float bhr_ = bhh[col], bhz_ = bhh[HH + col], bhn_ = bhh[2 * HH + col];
#pragma unroll
        for (int j = 0; j < 4; ++j) {
            int row = (lane >> 4) * 4 + j;
            size_t gidx = (size_t)(r0 + row) * HH + col;
            float rr = 1.f / (1.f + expf(-(air[j] + bir_ + ahr[j] + bhr_)));
            float zz = 1.f / (1.f + expf(-(aiz[j] + biz_ + ahz[j] + bhz_)));
            float nn2 = tanhf(ain[j] + bin_ + rr * (ahn[j] + bhn_));
            float hold = h[gidx];        // fp32 recurrent state (precision)
            float hnew = (1.f - zz) * nn2 + zz * hold;
            hv_[c][j] = hnew;
            h[gidx] = hnew;
        }
    }
    __syncthreads();
#pragma unroll
    for (int c = 0; c < 8; ++c) {
        int col = c * 16 + (lane & 15);
#pragma unroll
        for (int j = 0; j < 4; ++j) {
            int row = (lane >> 4) * 4 + j;
            int off = ((row * 128 + col) * 2) ^ ((row & 7) << 4);
            *(unsigned short*)((char*)bufB + off) = f2bf(hv_[c][j]);
        }
    }
    __syncthreads();

    // ---- phase 3: decoders
    bf16x8 xd[4];
#pragma unroll
    for (int kk = 0; kk < 4; ++kk) xd[kk] = LDA(bufB, kk);
    float pt[4] = {0, 0, 0, 0};
    float pf[NPF][4];
#pragma unroll
    for (int f = 0; f < NPF; ++f)
#pragma unroll
        for (int j = 0; j < 4; ++j) pf[f][j] = 0.f;
#pragma unroll
    for (int c = 0; c < 8; ++c) {
        f32x4 at = {0, 0, 0, 0}, ap = {0, 0, 0, 0};
#pragma unroll
        for (int kk = 0; kk < 4; ++kk) {
            bf16x8 bt = *(const bf16x8*)(pT1 + ((size_t)(c * 4 + kk) * 64 + lane) * 8);
            bf16x8 bp = *(const bf16x8*)(pP1 + ((size_t)(c * 4 + kk) * 64 + lane) * 8);
            at = MFMA(xd[kk], bt, at);
            ap = MFMA(xd[kk], bp, ap);
        }
        int col = c * 16 + (lane & 15);
        float b1 = tb1[col], b2 = pb1[col], w2 = tw2[col];
        float wp[NPF];
#pragma unroll
        for (int f = 0; f < NPF; ++f) wp[f] = pw2[col * NPF + f];
#pragma unroll
        for (int j = 0; j < 4; ++j) {
            float a = fmaxf(at[j] + b1, 0.f);
            pt[j] += a * w2;
            float p = fmaxf(ap[j] + b2, 0.f);
#pragma unroll
            for (int f = 0; f < NPF; ++f) pf[f][j] += p * wp[f];
        }
    }
#pragma unroll
    for (int o = 1; o <= 8; o <<= 1) {
#pragma unroll
        for (int j = 0; j < 4; ++j) {
            pt[j] += __shfl_xor(pt[j], o);
#pragma unroll
            for (int f = 0; f < NPF; ++f) pf[f][j] += __shfl_xor(pf[f][j], o);
        }
    }
    if ((lane & 15) == 0) {
        int g = lane >> 4;
#pragma unroll
        for (int j = 0; j < 4; ++j) {
            int gr = r0 + g * 4 + j;
            out_th[gr] = pt[j] + tb2[0];
#pragma unroll
            for (int f = 0; f < NPF; ++f)
                out_ph[(size_t)gr * NPF + f] = pf[f][j] + pb2[f];
        }
    }
#undef LDA
}

// ---------------------------------------------------------------------------
extern "C" void kernel_launch(void* const* d_in, const int* in_sizes, int n_in,
                              void* d_out, int out_size, void* d_ws, size_t ws_size,
                              hipStream_t stream) {
    const float* x     = (const float*)d_in[0];
    const int*   ei    = (const int*)d_in[1];
    const float* s1wl  = (const float*)d_in[2];
    const float* s1bl  = (const float*)d_in[3];
    const float* s1wr  = (const float*)d_in[4];
    const float* s2wl  = (const float*)d_in[5];
    const float* s2bl  = (const float*)d_in[6];
    const float* s2wr  = (const float*)d_in[7];
    const float* lng   = (const float*)d_in[8];
    const float* lnb   = (const float*)d_in[9];
    const float* g_wih = (const float*)d_in[10];
    const float* g_whh = (const float*)d_in[11];
    const float* g_bih = (const float*)d_in[12];
    const float* g_bhh = (const float*)d_in[13];
    const float* tw1   = (const float*)d_in[14];
    const float* tb1   = (const float*)d_in[15];
    const float* tw2   = (const float*)d_in[16];
    const float* tb2   = (const float*)d_in[17];
    const float* pw1   = (const float*)d_in[18];
    const float* pb1   = (const float*)d_in[19];
    const float* pw2   = (const float*)d_in[20];
    const float* pb2   = (const float*)d_in[21];

    char* ws = (char*)d_ws;
    size_t o = 0;
    auto alloc = [&](size_t bytes) {
        size_t r = o;
        o += (bytes + 255) & ~(size_t)255;
        return r;
    };
    int*            flag  = (int*)(ws + alloc(4));
    int*            deg   = (int*)(ws + alloc((size_t)NN * 4));
    int*            offs  = (int*)(ws + alloc((size_t)(NN + 1) * 4));
    int*            curs  = (int*)(ws + alloc((size_t)NN * 4));
    int*            csr   = (int*)(ws + alloc((size_t)EE * 4));
    float*          dinv  = (float*)(ws + alloc((size_t)NN * 4));
    unsigned short* pS2L  = (unsigned short*)(ws + alloc(8 * 4 * 64 * 8 * 2));
    unsigned short* pS2R  = (unsigned short*)(ws + alloc(8 * 4 * 64 * 8 * 2));
    unsigned short* pT1   = (unsigned short*)(ws + alloc(8 * 4 * 64 * 8 * 2));
    unsigned short* pP1   = (unsigned short*)(ws + alloc(8 * 4 * 64 * 8 * 2));
    unsigned short* pGI   = (unsigned short*)(ws + alloc(24 * 4 * 64 * 8 * 2));
    unsigned short* pGH   = (unsigned short*)(ws + alloc(24 * 4 * 64 * 8 * 2));
    float*          agg1  = (float*)(ws + alloc((size_t)NN * IND * 4));
    unsigned short* h1u   = (unsigned short*)(ws + alloc((size_t)NN * HH * 2));
    unsigned short* agg2u = (unsigned short*)(ws + alloc((size_t)NN * HH * 2));
    float*          hbuf  = (float*)(ws + alloc((size_t)NN * HH * 4));

    // Prep: CSR build + weight packing (identical work every call).
    detect_kernel<<<1, 256, 0, stream>>>(ei, flag, EE);
    hipMemsetAsync(deg, 0, (size_t)NN * 4, stream);
    count_deg_kernel<<<(EE + 255) / 256, 256, 0, stream>>>(ei, flag, deg, EE);
    scan_kernel<<<1, 1024, 0, stream>>>(deg, offs, curs, dinv, NN, EE);
    fill_csr_kernel<<<(EE + 255) / 256, 256, 0, stream>>>(ei, flag, curs, csr, EE);
    pack_kernel<<<(8 * 4 * 64 + 255) / 256, 256, 0, stream>>>(s2wl, pS2L, 8, 0);
    pack_kernel<<<(8 * 4 * 64 + 255) / 256, 256, 0, stream>>>(s2wr, pS2R, 8, 0);
    pack_kernel<<<(8 * 4 * 64 + 255) / 256, 256, 0, stream>>>(tw1, pT1, 8, 0);
    pack_kernel<<<(8 * 4 * 64 + 255) / 256, 256, 0, stream>>>(pw1, pP1, 8, 0);
    pack_kernel<<<(24 * 4 * 64 + 255) / 256, 256, 0, stream>>>(g_wih, pGI, 24, 1);
    pack_kernel<<<(24 * 4 * 64 + 255) / 256, 256, 0, stream>>>(g_whh, pGH, 24, 1);
    hipMemsetAsync(hbuf, 0, (size_t)NN * HH * 4, stream);

    float* out = (float*)d_out;
    for (int t = 0; t < TT; ++t) {
        const float* xt = x + (size_t)t * NN * IND;
        sage1_agg_kernel<<<(NN * 4 + 255) / 256, 256, 0, stream>>>(
            xt, offs, csr, dinv, agg1);
        sage1_gemm_kernel<<<NN / 8, 128, 0, stream>>>(
            agg1, xt, s1wl, s1bl, s1wr, h1u);
        sage2_agg_kernel<<<NN / 2, 128, 0, stream>>>(
            h1u, offs, csr, dinv, agg2u);
        fused_kernel<<<NN / 16, 64, 0, stream>>>(
            agg2u, h1u, pS2L, pS2R, s2bl, lng, lnb, pGI, pGH, g_bih, g_bhh,
            hbuf, pT1, pP1, tb1, tw2, tb2, pb1, pw2, pb2,
            out + (size_t)t * NN, out + (size_t)TT * NN + (size_t)t * NN * NPF);
    }
}

// Round 3
// 2691.449 us; speedup vs baseline: 3.4103x; 1.4493x over previous
//
#include <hip/hip_runtime.h>
#include <hip/hip_bf16.h>

#define TT 20
#define NN 50000
#define EE 800000
#define IND 16
#define HH 128
#define NPF 7
#define NB ((NN + 255) / 256)   // 196 scan blocks

typedef __attribute__((ext_vector_type(8))) short bf16x8;
typedef __attribute__((ext_vector_type(4))) float f32x4;
#define MFMA(a, b, c) __builtin_amdgcn_mfma_f32_16x16x32_bf16(a, b, c, 0, 0, 0)

__device__ __forceinline__ unsigned short f2bf(float f) {
    union { float f; unsigned u; } v; v.f = f;
    unsigned r = v.u + 0x7fffu + ((v.u >> 16) & 1u);
    return (unsigned short)(r >> 16);
}
__device__ __forceinline__ float bf2f(unsigned short u) {
    union { unsigned u; float f; } v; v.u = ((unsigned)u) << 16;
    return v.f;
}

// ---------------------------------------------------------------------------
// Edge-dtype detection (int64 vs int32) + CSR build.
__global__ void detect_kernel(const int* ei, int* flag, int E) {
    __shared__ int nz;
    if (threadIdx.x == 0) nz = 0;
    __syncthreads();
    for (int i = threadIdx.x; i < 1024 && i < E; i += blockDim.x)
        if (ei[2 * i + 1] != 0) atomicOr(&nz, 1);
    __syncthreads();
    if (threadIdx.x == 0) *flag = (nz == 0) ? 1 : 0;
}
__device__ __forceinline__ int edge_src(const int* ei, int e, int E, int f) {
    return f ? ei[2 * e] : ei[e];
}
__device__ __forceinline__ int edge_dst(const int* ei, int e, int E, int f) {
    return f ? ei[2 * (E + e)] : ei[E + e];
}
__global__ void count_deg_kernel(const int* ei, const int* flag, int* deg, int E) {
    int e = blockIdx.x * blockDim.x + threadIdx.x;
    if (e >= E) return;
    int f = *flag;
    atomicAdd(&deg[edge_dst(ei, e, E, f)], 1);
}

// Parallel scan, 3 stages.
__global__ __launch_bounds__(256) void sum_blocks_kernel(const int* deg, int* bsum) {
    int i = blockIdx.x * 256 + threadIdx.x;
    int v = (i < NN) ? deg[i] : 0;
#pragma unroll
    for (int o = 1; o <= 32; o <<= 1) v += __shfl_xor(v, o);
    __shared__ int ws[4];
    if ((threadIdx.x & 63) == 0) ws[threadIdx.x >> 6] = v;
    __syncthreads();
    if (threadIdx.x == 0) bsum[blockIdx.x] = ws[0] + ws[1] + ws[2] + ws[3];
}
__global__ __launch_bounds__(256) void scan_blocks_kernel(const int* bsum, int* bbase) {
    __shared__ int arr[256];
    int t = threadIdx.x;
    int v = (t < NB) ? bsum[t] : 0;
    arr[t] = v;
    __syncthreads();
    for (int off = 1; off < 256; off <<= 1) {
        int u = (t >= off) ? arr[t - off] : 0;
        __syncthreads();
        arr[t] += u;
        __syncthreads();
    }
    if (t < NB) bbase[t] = arr[t] - v;
}
__global__ __launch_bounds__(256) void offs_kernel(const int* deg, const int* bbase,
                                                   int* offs, int* cursor,
                                                   float* dinv, int E) {
    __shared__ int arr[256];
    int t = threadIdx.x;
    int i = blockIdx.x * 256 + t;
    int d = (i < NN) ? deg[i] : 0;
    arr[t] = d;
    __syncthreads();
    for (int off = 1; off < 256; off <<= 1) {
        int u = (t >= off) ? arr[t - off] : 0;
        __syncthreads();
        arr[t] += u;
        __syncthreads();
    }
    if (i < NN) {
        int o = bbase[blockIdx.x] + arr[t] - d;
        offs[i] = o;
        cursor[i] = o;
        dinv[i] = 1.0f / (float)(d > 1 ? d : 1);
        if (i == NN - 1) offs[NN] = E;
    }
}
__global__ void fill_csr_kernel(const int* ei, const int* flag, int* cursor,
                                int* csr, int E) {
    int e = blockIdx.x * blockDim.x + threadIdx.x;
    if (e >= E) return;
    int f = *flag;
    int s = edge_src(ei, e, E, f);
    int d = edge_dst(ei, e, E, f);
    int p = atomicAdd(&cursor[d], 1);
    csr[p] = s;
}

// ---------------------------------------------------------------------------
// Pack K=128 weights into MFMA B-fragment order.
// mode 0: B[k][n]=src[k*(tiles*16)+n]; mode 1: B[k][n]=src[n*128+k]
__global__ void pack_kernel(const float* src, unsigned short* dst, int tiles,
                            int mode) {
    int id = blockIdx.x * blockDim.x + threadIdx.x;
    if (id >= tiles * 4 * 64) return;
    int lane = id & 63, kk = (id >> 6) & 3, tile = id >> 8;
    int n = tile * 16 + (lane & 15);
    int kbase = kk * 32 + (lane >> 4) * 8;
    unsigned short out[8];
#pragma unroll
    for (int i = 0; i < 8; ++i) {
        int k = kbase + i;
        float v = mode ? src[n * HH + k] : src[k * (tiles * 16) + n];
        out[i] = f2bf(v);
    }
    *(uint4*)(dst + (size_t)id * 8) = *(uint4*)out;
}

// ---------------------------------------------------------------------------
// SAGE-1 (gather + GEMM fused), batched over chunk timesteps via blockIdx.y.
// 8 nodes / 128 threads. Gather: 16 threads/node, 4 edges in flight (float4).
__global__ __launch_bounds__(128) void sage1_kernel(
    const float* __restrict__ x, const int* __restrict__ offs,
    const int* __restrict__ csr, const float* __restrict__ dinv,
    const float* __restrict__ wl, const float* __restrict__ bl,
    const float* __restrict__ wr, unsigned short* __restrict__ h1c, int t0) {
    const int tid = threadIdx.x;
    const int ci = blockIdx.y;
    const float* xt = x + (size_t)(t0 + ci) * NN * IND;
    const int m0 = blockIdx.x * 8;
    __shared__ __align__(16) float sAgg[8][IND];
    __shared__ float sX[8][IND];
    {
        int r = tid >> 4, node = m0 + r;
        int l16 = tid & 15, sub = l16 >> 2, q = l16 & 3;
        int e1 = offs[node + 1];
        float4 acc = make_float4(0.f, 0.f, 0.f, 0.f);
        for (int e = offs[node] + sub; e < e1; e += 4) {
            float4 v = *(const float4*)(xt + (size_t)csr[e] * IND + q * 4);
            acc.x += v.x; acc.y += v.y; acc.z += v.z; acc.w += v.w;
        }
#pragma unroll
        for (int o = 4; o <= 8; o <<= 1) {
            acc.x += __shfl_xor(acc.x, o);
            acc.y += __shfl_xor(acc.y, o);
            acc.z += __shfl_xor(acc.z, o);
            acc.w += __shfl_xor(acc.w, o);
        }
        if (sub == 0) {
            float di = dinv[node];
            acc.x *= di; acc.y *= di; acc.z *= di; acc.w *= di;
            *(float4*)&sAgg[r][q * 4] = acc;
        }
        sX[r][l16] = xt[(size_t)node * IND + l16];
    }
    __syncthreads();
    const int col = tid;
    float acc[8];
    float b = bl[col];
#pragma unroll
    for (int m = 0; m < 8; ++m) acc[m] = b;
#pragma unroll
    for (int k = 0; k < IND; ++k) {
        float wlv = wl[k * HH + col];
        float wrv = wr[k * HH + col];
#pragma unroll
        for (int m = 0; m < 8; ++m) acc[m] += sAgg[m][k] * wlv + sX[m][k] * wrv;
    }
#pragma unroll
    for (int m = 0; m < 8; ++m)
        h1c[((size_t)ci * NN + m0 + m) * HH + col] = f2bf(fmaxf(acc[m], 0.f));
}

// SAGE-2 aggregation, batched. 1 wave/node, 4 nodes/block. 16B/lane loads,
// 4 edges in flight per wave; cross-group reduce via shfl.
__global__ __launch_bounds__(256) void sage2_agg_kernel(
    const unsigned short* __restrict__ h1c, const int* __restrict__ offs,
    const int* __restrict__ csr, const float* __restrict__ dinv,
    unsigned short* __restrict__ agg2c) {
    const int ci = blockIdx.y;
    const unsigned short* h1t = h1c + (size_t)ci * NN * HH;
    int wid = threadIdx.x >> 6, lane = threadIdx.x & 63;
    int n = blockIdx.x * 4 + wid;
    int eg = lane >> 4, part = lane & 15;
    int e0 = offs[n], e1 = offs[n + 1];
    float s[8] = {0.f, 0.f, 0.f, 0.f, 0.f, 0.f, 0.f, 0.f};
    for (int e = e0 + eg; e < e1; e += 4) {
        uint4 v = *(const uint4*)(h1t + (size_t)csr[e] * HH + part * 8);
        s[0] += bf2f((unsigned short)(v.x & 0xffff));
        s[1] += bf2f((unsigned short)(v.x >> 16));
        s[2] += bf2f((unsigned short)(v.y & 0xffff));
        s[3] += bf2f((unsigned short)(v.y >> 16));
        s[4] += bf2f((unsigned short)(v.z & 0xffff));
        s[5] += bf2f((unsigned short)(v.z >> 16));
        s[6] += bf2f((unsigned short)(v.w & 0xffff));
        s[7] += bf2f((unsigned short)(v.w >> 16));
    }
#pragma unroll
    for (int j = 0; j < 8; ++j) {
        s[j] += __shfl_xor(s[j], 16);
        s[j] += __shfl_xor(s[j], 32);
    }
    if (eg == 0) {
        float di = dinv[n];
        unsigned short o[8];
#pragma unroll
        for (int j = 0; j < 8; ++j) o[j] = f2bf(s[j] * di);
        *(uint4*)(agg2c + ((size_t)ci * NN + n) * HH + part * 8) = *(uint4*)o;
    }
}

// ---------------------------------------------------------------------------
// A-frag read from XOR-swizzled LDS tile (16 rows x 128 cols bf16).
#define LDA(buf, kk)                                                          \
    (*(const bf16x8*)((const char*)(buf) +                                    \
        (((lane & 15) * 256 + (kk) * 64 + (lane >> 4) * 16) ^                 \
         (((lane & 15) & 7) << 4))))

// GRU step: sage2-GEMM + LN + GRU. 1 wave, 16 nodes/block. Sequential over t.
// hallt may alias agg2t (block writes only rows it staged first).
__global__ __launch_bounds__(64) void gru_fused_kernel(
    const unsigned short* __restrict__ agg2t, const unsigned short* __restrict__ h1t,
    const unsigned short* __restrict__ pS2L, const unsigned short* __restrict__ pS2R,
    const float* __restrict__ s2bl, const float* __restrict__ lng,
    const float* __restrict__ lnb,
    const unsigned short* __restrict__ pGI, const unsigned short* __restrict__ pGH,
    const float* __restrict__ bih, const float* __restrict__ bhh,
    float* __restrict__ h, unsigned short* __restrict__ hallt) {
    const int lane = threadIdx.x;
    const int r0 = blockIdx.x * 16;
    __shared__ unsigned short bufA[16 * 128];  // agg2 -> enc
    __shared__ unsigned short bufB[16 * 128];  // h1
    __shared__ unsigned short bufH[16 * 128];  // h_old bf16

#pragma unroll
    for (int j = 0; j < 4; ++j) {
        int off = (lane + 64 * j) * 16;
        int row = off >> 8;
        int swz = off ^ ((row & 7) << 4);
        *(uint4*)((char*)bufA + swz) =
            *(const uint4*)((const char*)(agg2t + (size_t)r0 * HH) + off);
        *(uint4*)((char*)bufB + swz) =
            *(const uint4*)((const char*)(h1t + (size_t)r0 * HH) + off);
        const float* hs = h + (size_t)r0 * HH + (size_t)(off / 2);
        unsigned short tmp[8];
#pragma unroll
        for (int i = 0; i < 8; ++i) tmp[i] = f2bf(hs[i]);
        *(uint4*)((char*)bufH + swz) = *(uint4*)tmp;
    }
    __syncthreads();

    // ---- phase 1: enc = LN(relu(agg2@wl + bl + h1@wr))
    bf16x8 ae[4], ah[4];
#pragma unroll
    for (int kk = 0; kk < 4; ++kk) { ae[kk] = LDA(bufA, kk); ah[kk] = LDA(bufB, kk); }
    float vE[8][4];
    float sS[4] = {0, 0, 0, 0}, sQ[4] = {0, 0, 0, 0};
#pragma unroll
    for (int c = 0; c < 8; ++c) {
        f32x4 al = {0, 0, 0, 0}, ar = {0, 0, 0, 0};
#pragma unroll
        for (int kk = 0; kk < 4; ++kk) {
            bf16x8 bl = *(const bf16x8*)(pS2L + ((size_t)(c * 4 + kk) * 64 + lane) * 8);
            bf16x8 br = *(const bf16x8*)(pS2R + ((size_t)(c * 4 + kk) * 64 + lane) * 8);
            al = MFMA(ae[kk], bl, al);
            ar = MFMA(ah[kk], br, ar);
        }
        int col = c * 16 + (lane & 15);
        float bb = s2bl[col];
#pragma unroll
        for (int j = 0; j < 4; ++j) {
            float v = fmaxf(al[j] + ar[j] + bb, 0.f);
            vE[c][j] = v; sS[j] += v; sQ[j] += v * v;
        }
    }
#pragma unroll
    for (int o = 1; o <= 8; o <<= 1) {
#pragma unroll
        for (int j = 0; j < 4; ++j) {
            sS[j] += __shfl_xor(sS[j], o);
            sQ[j] += __shfl_xor(sQ[j], o);
        }
    }
    __syncthreads();
#pragma unroll
    for (int c = 0; c < 8; ++c) {
        int col = c * 16 + (lane & 15);
        float g = lng[col], b = lnb[col];
#pragma unroll
        for (int j = 0; j < 4; ++j) {
            float mu = sS[j] * (1.f / 128.f);
            float var = sQ[j] * (1.f / 128.f) - mu * mu;
            float ve = (vE[c][j] - mu) * rsqrtf(var + 1e-5f) * g + b;
            int row = (lane >> 4) * 4 + j;
            int off = ((row * 128 + col) * 2) ^ ((row & 7) << 4);
            *(unsigned short*)((char*)bufA + off) = f2bf(ve);
        }
    }
    __syncthreads();

    // ---- phase 2: GRU
    bf16x8 xe[4], xh[4];
#pragma unroll
    for (int kk = 0; kk < 4; ++kk) { xe[kk] = LDA(bufA, kk); xh[kk] = LDA(bufH, kk); }
#pragma unroll
    for (int c = 0; c < 8; ++c) {
        f32x4 air = {0,0,0,0}, aiz = {0,0,0,0}, ain = {0,0,0,0};
        f32x4 ahr = {0,0,0,0}, ahz = {0,0,0,0}, ahn = {0,0,0,0};
#pragma unroll
        for (int kk = 0; kk < 4; ++kk) {
            bf16x8 bir = *(const bf16x8*)(pGI + ((size_t)((c     ) * 4 + kk) * 64 + lane) * 8);
            bf16x8 biz = *(const bf16x8*)(pGI + ((size_t)((c +  8) * 4 + kk) * 64 + lane) * 8);
            bf16x8 bin = *(const bf16x8*)(pGI + ((size_t)((c + 16) * 4 + kk) * 64 + lane) * 8);
            bf16x8 bhr = *(const bf16x8*)(pGH + ((size_t)((c     ) * 4 + kk) * 64 + lane) * 8);
            bf16x8 bhz = *(const bf16x8*)(pGH + ((size_t)((c +  8) * 4 + kk) * 64 + lane) * 8);
            bf16x8 bhn = *(const bf16x8*)(pGH + ((size_t)((c + 16) * 4 + kk) * 64 + lane) * 8);
            air = MFMA(xe[kk], bir, air); aiz = MFMA(xe[kk], biz, aiz);
            ain = MFMA(xe[kk], bin, ain);
            ahr = MFMA(xh[kk], bhr, ahr); ahz = MFMA(xh[kk], bhz, ahz);
            ahn = MFMA(xh[kk], bhn, ahn);
        }
        int col = c * 16 + (lane & 15);
        float bir_ = bih[col], biz_ = bih[HH + col], bin_ = bih[2 * HH + col];
        float bhr_ = bhh[col], bhz_ = bhh[HH + col], bhn_ = bhh[2 * HH + col];
#pragma unroll
        for (int j = 0; j < 4; ++j) {
            int row = (lane >> 4) * 4 + j;
            size_t gidx = (size_t)(r0 + row) * HH + col;
            float rr = 1.f / (1.f + expf(-(air[j] + bir_ + ahr[j] + bhr_)));
            float zz = 1.f / (1.f + expf(-(aiz[j] + biz_ + ahz[j] + bhz_)));
            float nn2 = tanhf(ain[j] + bin_ + rr * (ahn[j] + bhn_));
            float hold = h[gidx];
            float hnew = (1.f - zz) * nn2 + zz * hold;
            h[gidx] = hnew;
            hallt[gidx] = f2bf(hnew);
        }
    }
}

// Decoders, batched over the chunk: 16 rows/block from hall (bf16).
__global__ __launch_bounds__(64) void dec_kernel(
    const unsigned short* __restrict__ hall,
    const unsigned short* __restrict__ pT1, const unsigned short* __restrict__ pP1,
    const float* __restrict__ tb1, const float* __restrict__ tw2,
    const float* __restrict__ tb2, const float* __restrict__ pb1,
    const float* __restrict__ pw2, const float* __restrict__ pb2,
    float* __restrict__ out_th, float* __restrict__ out_ph, int t0) {
    const int lane = threadIdx.x;
    const int rc = blockIdx.x * 16;          // row within chunk
    const int ci = rc / NN;
    const int n0 = rc - ci * NN;
    const int tg = t0 + ci;
    __shared__ unsigned short bufB[16 * 128];
#pragma unroll
    for (int j = 0; j < 4; ++j) {
        int off = (lane + 64 * j) * 16;
        int row = off >> 8;
        int swz = off ^ ((row & 7) << 4);
        *(uint4*)((char*)bufB + swz) =
            *(const uint4*)((const char*)(hall + (size_t)rc * HH) + off);
    }
    __syncthreads();
    bf16x8 xd[4];
#pragma unroll
    for (int kk = 0; kk < 4; ++kk) xd[kk] = LDA(bufB, kk);
    float pt[4] = {0, 0, 0, 0};
    float pf[NPF][4];
#pragma unroll
    for (int f = 0; f < NPF; ++f)
#pragma unroll
        for (int j = 0; j < 4; ++j) pf[f][j] = 0.f;
#pragma unroll
    for (int c = 0; c < 8; ++c) {
        f32x4 at = {0, 0, 0, 0}, ap = {0, 0, 0, 0};
#pragma unroll
        for (int kk = 0; kk < 4; ++kk) {
            bf16x8 bt = *(const bf16x8*)(pT1 + ((size_t)(c * 4 + kk) * 64 + lane) * 8);
            bf16x8 bp = *(const bf16x8*)(pP1 + ((size_t)(c * 4 + kk) * 64 + lane) * 8);
            at = MFMA(xd[kk], bt, at);
            ap = MFMA(xd[kk], bp, ap);
        }
        int col = c * 16 + (lane & 15);
        float b1 = tb1[col], b2 = pb1[col], w2 = tw2[col];
        float wp[NPF];
#pragma unroll
        for (int f = 0; f < NPF; ++f) wp[f] = pw2[col * NPF + f];
#pragma unroll
        for (int j = 0; j < 4; ++j) {
            float a = fmaxf(at[j] + b1, 0.f);
            pt[j] += a * w2;
            float p = fmaxf(ap[j] + b2, 0.f);
#pragma unroll
            for (int f = 0; f < NPF; ++f) pf[f][j] += p * wp[f];
        }
    }
#pragma unroll
    for (int o = 1; o <= 8; o <<= 1) {
#pragma unroll
        for (int j = 0; j < 4; ++j) {
            pt[j] += __shfl_xor(pt[j], o);
#pragma unroll
            for (int f = 0; f < NPF; ++f) pf[f][j] += __shfl_xor(pf[f][j], o);
        }
    }
    if ((lane & 15) == 0) {
        int g = lane >> 4;
#pragma unroll
        for (int j = 0; j < 4; ++j) {
            int gr = n0 + g * 4 + j;
            out_th[(size_t)tg * NN + gr] = pt[j] + tb2[0];
#pragma unroll
            for (int f = 0; f < NPF; ++f)
                out_ph[((size_t)tg * NN + gr) * NPF + f] = pf[f][j] + pb2[f];
        }
    }
}
#undef LDA

// ---------------------------------------------------------------------------
extern "C" void kernel_launch(void* const* d_in, const int* in_sizes, int n_in,
                              void* d_out, int out_size, void* d_ws, size_t ws_size,
                              hipStream_t stream) {
    const float* x     = (const float*)d_in[0];
    const int*   ei    = (const int*)d_in[1];
    const float* s1wl  = (const float*)d_in[2];
    const float* s1bl  = (const float*)d_in[3];
    const float* s1wr  = (const float*)d_in[4];
    const float* s2wl  = (const float*)d_in[5];
    const float* s2bl  = (const float*)d_in[6];
    const float* s2wr  = (const float*)d_in[7];
    const float* lng   = (const float*)d_in[8];
    const float* lnb   = (const float*)d_in[9];
    const float* g_wih = (const float*)d_in[10];
    const float* g_whh = (const float*)d_in[11];
    const float* g_bih = (const float*)d_in[12];
    const float* g_bhh = (const float*)d_in[13];
    const float* tw1   = (const float*)d_in[14];
    const float* tb1   = (const float*)d_in[15];
    const float* tw2   = (const float*)d_in[16];
    const float* tb2   = (const float*)d_in[17];
    const float* pw1   = (const float*)d_in[18];
    const float* pb1   = (const float*)d_in[19];
    const float* pw2   = (const float*)d_in[20];
    const float* pb2   = (const float*)d_in[21];

    char* ws = (char*)d_ws;
    size_t o = 0;
    auto alloc = [&](size_t bytes) {
        size_t r = o;
        o += (bytes + 255) & ~(size_t)255;
        return r;
    };
    int*            flag  = (int*)(ws + alloc(4));
    int*            deg   = (int*)(ws + alloc((size_t)NN * 4));
    int*            offs  = (int*)(ws + alloc((size_t)(NN + 1) * 4));
    int*            curs  = (int*)(ws + alloc((size_t)NN * 4));
    int*            csr   = (int*)(ws + alloc((size_t)EE * 4));
    float*          dinv  = (float*)(ws + alloc((size_t)NN * 4));
    int*            bsum  = (int*)(ws + alloc((size_t)NB * 4));
    int*            bbase = (int*)(ws + alloc((size_t)NB * 4));
    unsigned short* pS2L  = (unsigned short*)(ws + alloc(8 * 4 * 64 * 8 * 2));
    unsigned short* pS2R  = (unsigned short*)(ws + alloc(8 * 4 * 64 * 8 * 2));
    unsigned short* pT1   = (unsigned short*)(ws + alloc(8 * 4 * 64 * 8 * 2));
    unsigned short* pP1   = (unsigned short*)(ws + alloc(8 * 4 * 64 * 8 * 2));
    unsigned short* pGI   = (unsigned short*)(ws + alloc(24 * 4 * 64 * 8 * 2));
    unsigned short* pGH   = (unsigned short*)(ws + alloc(24 * 4 * 64 * 8 * 2));
    float*          hbuf  = (float*)(ws + alloc((size_t)NN * HH * 4));

    // Chunk size from remaining workspace: per-t = h1c + agg2c (hall aliases agg2c).
    const size_t per_t = 2ull * NN * HH * 2;
    size_t avail = (o < ws_size) ? ws_size - o : 0;
    int C = (int)(avail / per_t);
    if (C < 1) C = 1;
    if (C > TT) C = TT;
    unsigned short* h1c   = (unsigned short*)(ws + alloc((size_t)C * NN * HH * 2));
    unsigned short* agg2c = (unsigned short*)(ws + alloc((size_t)C * NN * HH * 2));
    unsigned short* hallc = agg2c;  // alias: gru writes h over consumed agg2 rows

    // Prep (identical every call).
    detect_kernel<<<1, 256, 0, stream>>>(ei, flag, EE);
    hipMemsetAsync(deg, 0, (size_t)NN * 4, stream);
    count_deg_kernel<<<(EE + 255) / 256, 256, 0, stream>>>(ei, flag, deg, EE);
    sum_blocks_kernel<<<NB, 256, 0, stream>>>(deg, bsum);
    scan_blocks_kernel<<<1, 256, 0, stream>>>(bsum, bbase);
    offs_kernel<<<NB, 256, 0, stream>>>(deg, bbase, offs, curs, dinv, EE);
    fill_csr_kernel<<<(EE + 255) / 256, 256, 0, stream>>>(ei, flag, curs, csr, EE);
    pack_kernel<<<(8 * 4 * 64 + 255) / 256, 256, 0, stream>>>(s2wl, pS2L, 8, 0);
    pack_kernel<<<(8 * 4 * 64 + 255) / 256, 256, 0, stream>>>(s2wr, pS2R, 8, 0);
    pack_kernel<<<(8 * 4 * 64 + 255) / 256, 256, 0, stream>>>(tw1, pT1, 8, 0);
    pack_kernel<<<(8 * 4 * 64 + 255) / 256, 256, 0, stream>>>(pw1, pP1, 8, 0);
    pack_kernel<<<(24 * 4 * 64 + 255) / 256, 256, 0, stream>>>(g_wih, pGI, 24, 1);
    pack_kernel<<<(24 * 4 * 64 + 255) / 256, 256, 0, stream>>>(g_whh, pGH, 24, 1);
    hipMemsetAsync(hbuf, 0, (size_t)NN * HH * 4, stream);

    float* out = (float*)d_out;
    for (int t0 = 0; t0 < TT; t0 += C) {
        int Cc = TT - t0 < C ? TT - t0 : C;
        dim3 g1(NN / 8, Cc), g2(NN / 4, Cc);
        sage1_kernel<<<g1, 128, 0, stream>>>(x, offs, csr, dinv, s1wl, s1bl,
                                             s1wr, h1c, t0);
        sage2_agg_kernel<<<g2, 256, 0, stream>>>(h1c, offs, csr, dinv, agg2c);
        for (int ci = 0; ci < Cc; ++ci) {
            size_t co = (size_t)ci * NN * HH;
            gru_fused_kernel<<<NN / 16, 64, 0, stream>>>(
                agg2c + co, h1c + co, pS2L, pS2R, s2bl, lng, lnb, pGI, pGH,
                g_bih, g_bhh, hbuf, hallc + co);
        }
        dec_kernel<<<(size_t)Cc * NN / 16, 64, 0, stream>>>(
            hallc, pT1, pP1, tb1, tw2, tb2, pb1, pw2, pb2,
            out, out + (size_t)TT * NN, t0);
    }
}